// Round 6
// baseline (136.306 us; speedup 1.0000x reference)
//
#include <hip/hip_runtime.h>
#include <cmath>

#define P 5
#define LBV 0.0f
#define UBV 0.5f
#define RFV 1.03f
#define ALPHA 0.1f
#define OMEGA 0.05f
#define BETA 0.05f
#define MU 0.01f
#define NTHR 256
#define CPW 4                 // chunks (of 64 samples) per wave

#define AS1 __attribute__((address_space(1)))
#define AS3 __attribute__((address_space(3)))

// tanh via HW v_exp_f32 + v_rcp_f32. For |x| large, exp(-2|x|)->0 => r->1.
__device__ __forceinline__ float fast_tanh(float x) {
    float ax = fabsf(x);
    float t  = __expf(-2.0f * ax);
    float r  = (1.0f - t) * __builtin_amdgcn_rcpf(1.0f + t);
    return copysignf(r, x);
}

// Persistent pipelined version. R2/R4/R5 all plateaued at ~34us kernel time
// regardless of barrier structure -> the cost is block turnover (LDS frees
// only at full-block retire; one tiny pass per wave exposes every launch and
// store-drain transient 8x per CU) plus read-latency underflight. Here each
// wave owns CPW=4 chunks of 64 samples with a private double-buffered LDS
// region and prefetches chunk c+1's DMA batch while computing chunk c.
// vmcnt FIFO accounting (in-order retire): batch = 10 vm ops (9 DMA + x1),
// stores = 8/chunk. At iter-c wait: [batch c][stores c-1][batch c+1] ->
// vmcnt(10) drains batch c. Last iter: [batch 3][stores 2] -> vmcnt(8).
__global__ __launch_bounds__(NTHR, 2) void portfolio_kernel(
    const float* __restrict__ x1,
    const float* __restrict__ x2,
    const float* __restrict__ eps,
    const float* __restrict__ W,
    float* __restrict__ out, int B)
{
    __shared__ alignas(16) float sBuf[4][2][1920];   // [wave][buf][x2:1600|eps:320]

    const int tid  = threadIdx.x;
    const int lane = tid & 63;
    const int wv   = tid >> 6;                        // uniform per wave
    const int s0   = blockIdx.x * (4 * CPW * 64) + wv * (CPW * 64);
    const float* epsl = eps + (size_t)3 * B * P;

    // Issue one chunk's staging batch: 9 DMA ops + 1 x1 load = 10 vm ops.
    auto issue = [&](int c, int buf) -> float {
        const int sc = s0 + c * 64;
        float xv = x1[sc + lane];
        const float* gx2 = x2 + (size_t)sc * (P * P);     // 1600 floats
        float* ldsx = &sBuf[wv][buf][0];
        #pragma unroll
        for (int i = 0; i < 6; ++i)
            __builtin_amdgcn_global_load_lds((const AS1 void*)(gx2 + i * 256 + lane * 4),
                                             (AS3 void*)(ldsx + i * 256), 16, 0, 0);
        __builtin_amdgcn_global_load_lds((const AS1 void*)(gx2 + 1536 + lane),
                                         (AS3 void*)(ldsx + 1536), 4, 0, 0);
        const float* ge = epsl + (size_t)sc * P;          // 320 floats
        float* ldse = &sBuf[wv][buf][1600];
        __builtin_amdgcn_global_load_lds((const AS1 void*)(ge + lane * 4),
                                         (AS3 void*)(ldse), 16, 0, 0);
        __builtin_amdgcn_global_load_lds((const AS1 void*)(ge + 256 + lane),
                                         (AS3 void*)(ldse + 256), 4, 0, 0);
        return xv;
    };

    float x1cur = issue(0, 0);
    float x1nxt = 0.0f;

    #pragma unroll
    for (int c = 0; c < CPW; ++c) {
        const int buf = c & 1;
        if (c + 1 < CPW) x1nxt = issue(c + 1, (c + 1) & 1);

        __builtin_amdgcn_sched_barrier(0);
        if (c + 1 < CPW) __builtin_amdgcn_s_waitcnt(0x0F7A);  // vmcnt(10)
        else             __builtin_amdgcn_s_waitcnt(0x0F78);  // vmcnt(8)
        __builtin_amdgcn_sched_barrier(0);

        float* ldsx = &sBuf[wv][buf][0];
        float* ldse = &sBuf[wv][buf][1600];
        const int sc = s0 + c * 64;

        // Own x2 row (lane stride 25 words -> 2 lanes/bank, free).
        float r2[P * P];
        #pragma unroll
        for (int i = 0; i < P * P; ++i) r2[i] = ldsx[lane * (P * P) + i];
        float e[P];
        #pragma unroll
        for (int j = 0; j < P; ++j) e[j] = ldse[lane * P + j];

        // Ce[i] = sum_j x2[i][j] * eps[j]
        float Ce[P];
        #pragma unroll
        for (int i = 0; i < P; ++i) {
            float s = 0.0f;
            #pragma unroll
            for (int j = 0; j < P; ++j) s = fmaf(r2[i * P + j], e[j], s);
            Ce[i] = s;
        }

        float R[P], h[P];
        #pragma unroll
        for (int i = 0; i < P; ++i) { R[i] = MU + Ce[i]; h[i] = R[i]; }

        // 3 bias-free Linear(5,5) + tanh. W[3] wave-uniform -> s_loads.
        const float* Wl = W + 3 * 3 * P * P;
        #pragma unroll
        for (int l = 0; l < 3; ++l) {
            float hn[P];
            #pragma unroll
            for (int i = 0; i < P; ++i) {
                float s = 0.0f;
                #pragma unroll
                for (int j = 0; j < P; ++j) s = fmaf(h[j], Wl[l * P * P + i * P + j], s);
                hn[i] = fast_tanh(s);
            }
            #pragma unroll
            for (int i = 0; i < P; ++i) h[i] = hn[i];
        }

        // softmax over P — h in (-1,1) so no max-subtraction needed
        float w[P], ssum = 0.0f;
        #pragma unroll
        for (int i = 0; i < P; ++i) { w[i] = __expf(h[i]); ssum += w[i]; }
        float rs = __builtin_amdgcn_rcpf(ssum);
        #pragma unroll
        for (int i = 0; i < P; ++i) w[i] *= rs;

        // water-filling rebalance; break==freeze (matches reference semantics)
        float oldv[P], nw[P];
        #pragma unroll
        for (int i = 0; i < P; ++i) {
            oldv[i] = w[i];
            nw[i]   = fminf(fmaxf(w[i], LBV), UBV);
        }
        #pragma unroll
        for (int it = 0; it < 8; ++it) {
            float leftover = 0.0f;
            #pragma unroll
            for (int i = 0; i < P; ++i) leftover += oldv[i] - nw[i];
            float mk[P], msum = 0.0f;
            #pragma unroll
            for (int i = 0; i < P; ++i) {
                mk[i] = (nw[i] != UBV) ? nw[i] : 0.0f;
                msum += mk[i];
            }
            float scale = leftover * __builtin_amdgcn_rcpf(msum);
            float n2[P];
            #pragma unroll
            for (int i = 0; i < P; ++i) n2[i] = fmaf(scale, mk[i], nw[i]);
            bool cont = false;
            #pragma unroll
            for (int i = 0; i < P; ++i) cont = cont || (n2[i] > UBV);
            #pragma unroll
            for (int i = 0; i < P; ++i) {
                oldv[i] = n2[i];
                nw[i]   = cont ? fminf(fmaxf(n2[i], LBV), UBV) : n2[i];
            }
            if (!cont) break;
        }

        // wealth = x1 * RF * sum_i nw[i] * (1 + R[i])  (coalesced store)
        float ws = 0.0f;
        #pragma unroll
        for (int i = 0; i < P; ++i) ws = fmaf(nw[i], 1.0f + R[i], ws);
        out[sc + lane] = x1cur * ws * RFV;

        // cov back into just-consumed buffer (same-wave DS pipe order is
        // enough; buffer not DMA'd again until iter c+1 issues batch c+2,
        // by which time these ds ops are lgkmcnt-retired).
        float ce2[P];
        #pragma unroll
        for (int j = 0; j < P; ++j) ce2[j] = Ce[j] * Ce[j];
        #pragma unroll
        for (int i = 0; i < P; ++i) {
            #pragma unroll
            for (int j = 0; j < P; ++j)
                ldsx[lane * (P * P) + i * P + j] =
                    fmaf(BETA, ce2[j], fmaf(ALPHA, r2[i * P + j], OMEGA));
        }

        // coalesced store-out: 6 float4 + 1 dword = 7 stores (8 with wealth)
        float* gout = out + B + (size_t)sc * (P * P);
        const float4* s4 = (const float4*)ldsx;
        float4* g4 = (float4*)gout;
        #pragma unroll
        for (int r = 0; r < 6; ++r)
            g4[r * 64 + lane] = s4[r * 64 + lane];
        gout[1536 + lane] = ldsx[1536 + lane];

        x1cur = x1nxt;
    }
}

extern "C" void kernel_launch(void* const* d_in, const int* in_sizes, int n_in,
                              void* d_out, int out_size, void* d_ws, size_t ws_size,
                              hipStream_t stream) {
    const float* x1  = (const float*)d_in[0];
    const float* x2  = (const float*)d_in[1];
    const float* eps = (const float*)d_in[2];
    const float* W   = (const float*)d_in[3];
    float* out = (float*)d_out;
    const int B = in_sizes[0];                   // 524288
    const int blocks = B / (4 * CPW * 64);       // 512 -> 2 blocks/CU
    portfolio_kernel<<<blocks, NTHR, 0, stream>>>(x1, x2, eps, W, out, B);
}